// Round 7
// baseline (55.595 us; speedup 1.0000x reference)
//
#include <hip/hip_runtime.h>
#include <hip/hip_bf16.h>

constexpr int Bb  = 8;
constexpr int Nn  = 2048;
constexpr int FIN = 128;
constexpr int FOUT = 64;
constexpr float LOG2E = 1.4426950408889634f;

typedef __bf16 bf16x8 __attribute__((ext_vector_type(8)));
typedef __bf16 bf16x2 __attribute__((ext_vector_type(2)));
typedef float  f32x4  __attribute__((ext_vector_type(4)));
typedef int    i32x4  __attribute__((ext_vector_type(4)));
typedef unsigned int u32;

__device__ __forceinline__ u32 f2bf_bits(float f) {
    u32 u = __builtin_bit_cast(u32, f);
    return (u + 0x7FFFu + ((u >> 16) & 1u)) >> 16;  // RNE
}

// Kernel 1: Wh = h@W (fp32 accum) -> bf16 in MFMA B-fragment order.
// h delivered via LDS staging (coalesced float4 vector loads + uniform
// ds_read broadcast) instead of the scalar s_load path.
// fs = (Wh @ a[:64]) * log2e, fd = (Wh @ a[64:]) * log2e.
__global__ __launch_bounds__(256) void gat_k1(
        const float* __restrict__ h, const float* __restrict__ W,
        const float* __restrict__ a, __bf16* __restrict__ whfrag,
        float* __restrict__ fs, float* __restrict__ fd) {
    const int blk = blockIdx.x;
    const int b   = blk >> 6;
    const int t32 = blk & 63;
    const int n0  = t32 * 32;
    const int l   = threadIdx.x & 63;
    const int w   = __builtin_amdgcn_readfirstlane((int)(threadIdx.x >> 6));

    __shared__ __align__(16) float hT[32][FIN];   // 16 KB

    // stage 32x128 h-tile: 1024 float4, 4 per thread, coalesced
    {
        const float4* hb = reinterpret_cast<const float4*>(h + (size_t)(b * Nn + n0) * FIN);
        float4* dst = reinterpret_cast<float4*>(&hT[0][0]);
#pragma unroll
        for (int k = 0; k < 4; ++k) {
            const int flat = threadIdx.x + k * 256;
            dst[flat] = hb[flat];
        }
    }
    __syncthreads();

    const float a0 = a[l];
    const float a1 = a[FOUT + l];

    float acc[8];
#pragma unroll
    for (int r = 0; r < 8; ++r) acc[r] = 0.f;

#pragma unroll 1
    for (int c0 = 0; c0 < FIN; c0 += 32) {
        float wreg[32];
#pragma unroll
        for (int cc = 0; cc < 32; ++cc) wreg[cc] = W[(c0 + cc) * FOUT + l];
#pragma unroll
        for (int r = 0; r < 8; ++r) {
            const int row = w * 8 + r;
#pragma unroll
            for (int cc = 0; cc < 32; ++cc)
                acc[r] = fmaf(hT[row][c0 + cc], wreg[cc], acc[r]);  // LDS broadcast
        }
    }

#pragma unroll
    for (int r = 0; r < 8; ++r) {
        float s0 = acc[r] * a0;
        float s1 = acc[r] * a1;
#pragma unroll
        for (int off = 32; off >= 1; off >>= 1) {
            s0 += __shfl_xor(s0, off, 64);
            s1 += __shfl_xor(s1, off, 64);
        }
        if (l == 0) {
            fs[b * Nn + n0 + w * 8 + r] = s0 * LOG2E;
            fd[b * Nn + n0 + w * 8 + r] = s1 * LOG2E;
        }
    }

    u32 pk[4];
#pragma unroll
    for (int i = 0; i < 4; ++i)
        pk[i] = f2bf_bits(acc[2 * i]) | (f2bf_bits(acc[2 * i + 1]) << 16);
    const int slotg = ((b * 64 + t32) * 4 + (l >> 4)) * 64 + ((w << 4) | (l & 15));
    reinterpret_cast<uint4*>(whfrag)[slotg] = make_uint4(pk[0], pk[1], pk[2], pk[3]);
}

// Kernel 2: same wave-private dbuf+fence structure as r5, but adj loads are
// 2 rows x 512B contiguous per instruction (lane = 32-per-row), j-tile 128:
// per iter a wave loads 16 rows x 512B in 8 x dwordx4 instructions and
// computes 32 p/lane. 4 iters cover the wave's 512-j quarter.
__global__ __launch_bounds__(256, 3) void gat_k2(
        const int* __restrict__ adj, const __bf16* __restrict__ whfrag,
        const float* __restrict__ fs, const float* __restrict__ fd,
        float* __restrict__ out) {
    const int blk = blockIdx.x;              // 1024 blocks
    const int b   = blk >> 7;
    const int i0  = (blk & 127) * 16;
    const int l   = threadIdx.x & 63;
    const int w   = __builtin_amdgcn_readfirstlane((int)(threadIdx.x >> 6)); // j quarter

    __shared__ __align__(16) char  aLDS[4 * 8192];  // per-wave 2x4KB double buffer
    __shared__ f32x4 comb[4][4][64];                // 16 KB combine buffer
    __shared__ float zpart[4][16];

    const int hi = l >> 5;      // row parity within a 2-row load
    const int lo = l & 31;      // 32 lanes span 128 cols (512 B)
    const int g  = l >> 4;      // epilogue row group
    const int jc = l & 15;      // epilogue col

    char* myA = aLDS + w * 8192;

    float fs_loc[8];
#pragma unroll
    for (int t = 0; t < 8; ++t) fs_loc[t] = fs[b * Nn + i0 + 2 * t + hi];

    const int    jq0  = w * 512;
    const float* fdp  = fd + b * Nn + jq0 + lo * 4;
    const int*   adj0 = adj + (size_t)(b * Nn + i0 + hi) * Nn + jq0 + lo * 4;

    const bf16x8* bfr = reinterpret_cast<const bf16x8*>(whfrag)
                        + (size_t)(b * 256) * 64 + l;

    f32x4 acc[4] = {{0,0,0,0},{0,0,0,0},{0,0,0,0},{0,0,0,0}};
    f32x4 accz   = {0.f, 0.f, 0.f, 0.f};

    bf16x8 onesv;
#pragma unroll
    for (int i = 0; i < 8; ++i) onesv[i] = (__bf16)1.0f;

    i32x4 adjT[2][8];
    f32x4 fdQ[2];

#pragma unroll
    for (int t = 0; t < 8; ++t)
        adjT[0][t] = *reinterpret_cast<const i32x4*>(adj0 + (size_t)(2 * t) * Nn);
    fdQ[0] = *reinterpret_cast<const f32x4*>(fdp);

#pragma unroll 2
    for (int it = 0; it < 4; ++it) {
        const int cur = it & 1, nxt = cur ^ 1;   // compile-time under unroll 2
        if (it < 3) {  // 1-ahead prefetch, next 128-j window (512 B further)
#pragma unroll
            for (int t = 0; t < 8; ++t)
                adjT[nxt][t] = *reinterpret_cast<const i32x4*>(
                                   adj0 + (size_t)(2 * t) * Nn + (it + 1) * 128);
            fdQ[nxt] = *reinterpret_cast<const f32x4*>(fdp + (it + 1) * 128);
        }

        // phase A: 32 p per lane -> bf16 pairs -> swizzled LDS (16x128 tile)
        char* buf = myA + cur * 4096;
#pragma unroll
        for (int t = 0; t < 8; ++t) {
            const int row = 2 * t + hi;
            float pv[4];
#pragma unroll
            for (int q = 0; q < 4; ++q) {
                float e  = fs_loc[t] + fdQ[cur][q];
                float lr = fmaxf(e, 0.2f * e);       // leaky relu (scale-safe)
                float p  = exp2f(lr);                // fs/fd pre-scaled by log2e
                pv[q] = (adjT[cur][t][q] > 0) ? p : 0.f;
            }
            u32 w0 = __builtin_bit_cast(u32, (bf16x2){(__bf16)pv[0], (__bf16)pv[1]});
            u32 w1 = __builtin_bit_cast(u32, (bf16x2){(__bf16)pv[2], (__bf16)pv[3]});
            const int boff = (row * 256 + lo * 8) ^ ((row & 7) << 4);  // XOR swizzle
            *reinterpret_cast<uint2*>(buf + boff) = make_uint2(w0, w1);
        }

        // fence: this wave's ds_writes committed before phase-B ds_reads.
        asm volatile("s_waitcnt lgkmcnt(0)" ::: "memory");
        __builtin_amdgcn_sched_barrier(0x20);   // VMEM reads may still hoist

        // phase B: 4 kb x (ds_read_b128 + 5 MFMA)
#pragma unroll
        for (int kb = 0; kb < 4; ++kb) {
            const int rbyte = (((l & 15) * 256 + kb * 64 + (l >> 4) * 16)
                               ^ ((l & 7) << 4));
            bf16x8 av = *reinterpret_cast<const bf16x8*>(buf + rbyte);
            const int t32 = w * 16 + it * 4 + kb;   // global K-block index
#pragma unroll
            for (int o16 = 0; o16 < 4; ++o16)
                acc[o16] = __builtin_amdgcn_mfma_f32_16x16x32_bf16(
                               av, bfr[(t32 * 4 + o16) * 64], acc[o16], 0, 0, 0);
            accz = __builtin_amdgcn_mfma_f32_16x16x32_bf16(av, onesv, accz, 0, 0, 0);
        }
    }

    // Z partials: accz D-frag row=(l>>4)*4+r, col=l&15 (all cols identical)
    if ((l & 15) == 0) {
#pragma unroll
        for (int r = 0; r < 4; ++r) zpart[w][(l >> 4) * 4 + r] = accz[r];
    }
#pragma unroll
    for (int o16 = 0; o16 < 4; ++o16) comb[w][o16][l] = acc[o16];
    __syncthreads();

    // wave w finalizes output column block o16 = w
    f32x4 res = comb[0][w][l];
#pragma unroll
    for (int wp = 1; wp < 4; ++wp) res += comb[wp][w][l];

#pragma unroll
    for (int r = 0; r < 4; ++r) {
        const int row = g * 4 + r;                     // C/D: row=(l>>4)*4+r, col=l&15
        float z = zpart[0][row] + zpart[1][row] + zpart[2][row] + zpart[3][row];
        float v = res[r] / z;
        v = v > 0.f ? v : expm1f(v);                   // ELU
        out[(size_t)(b * Nn + i0 + row) * FOUT + w * 16 + jc] = v;
    }
}

extern "C" void kernel_launch(void* const* d_in, const int* in_sizes, int n_in,
                              void* d_out, int out_size, void* d_ws, size_t ws_size,
                              hipStream_t stream) {
    const float* h   = (const float*)d_in[0];
    const int*   adj = (const int*)d_in[1];
    const float* W   = (const float*)d_in[2];
    const float* a   = (const float*)d_in[3];
    float* out = (float*)d_out;

    __bf16* whfrag = (__bf16*)d_ws;                                   // 2 MB
    float*  fs     = (float*)((char*)d_ws + (size_t)Bb * Nn * FOUT * 2);
    float*  fd     = fs + Bb * Nn;

    gat_k1<<<dim3(Bb * 64), dim3(256), 0, stream>>>(h, W, a, whfrag, fs, fd);
    gat_k2<<<dim3(Bb * 128), dim3(256), 0, stream>>>(adj, whfrag, fs, fd, out);
}

// Round 8
// 47.585 us; speedup vs baseline: 1.1683x; 1.1683x over previous
//
#include <hip/hip_runtime.h>
#include <hip/hip_bf16.h>

constexpr int Bb  = 8;
constexpr int Nn  = 2048;
constexpr int FIN = 128;
constexpr int FOUT = 64;
constexpr float LOG2E = 1.4426950408889634f;

typedef __bf16 bf16x8 __attribute__((ext_vector_type(8)));
typedef __bf16 bf16x2 __attribute__((ext_vector_type(2)));
typedef float  f32x4  __attribute__((ext_vector_type(4)));
typedef int    i32x4  __attribute__((ext_vector_type(4)));
typedef unsigned int u32;

__device__ __forceinline__ u32 f2bf_bits(float f) {
    u32 u = __builtin_bit_cast(u32, f);
    return (u + 0x7FFFu + ((u >> 16) & 1u)) >> 16;  // RNE
}

// Kernel 1: Wh = h@W (fp32 accum) -> bf16 in MFMA B-fragment order.
// h via LDS staging (coalesced float4 loads + uniform ds_read broadcast),
// NOT the scalar s_load path (dependent cold-HBM SMEM chains).
// fs = (Wh @ a[:64]) * log2e, fd = (Wh @ a[64:]) * log2e.
__global__ __launch_bounds__(256) void gat_k1(
        const float* __restrict__ h, const float* __restrict__ W,
        const float* __restrict__ a, __bf16* __restrict__ whfrag,
        float* __restrict__ fs, float* __restrict__ fd) {
    const int blk = blockIdx.x;
    const int b   = blk >> 6;
    const int t32 = blk & 63;
    const int n0  = t32 * 32;
    const int l   = threadIdx.x & 63;
    const int w   = __builtin_amdgcn_readfirstlane((int)(threadIdx.x >> 6));

    __shared__ __align__(16) float hT[32][FIN];   // 16 KB

    {
        const float4* hb = reinterpret_cast<const float4*>(h + (size_t)(b * Nn + n0) * FIN);
        float4* dst = reinterpret_cast<float4*>(&hT[0][0]);
#pragma unroll
        for (int k = 0; k < 4; ++k) {
            const int flat = threadIdx.x + k * 256;
            dst[flat] = hb[flat];
        }
    }
    __syncthreads();

    const float a0 = a[l];
    const float a1 = a[FOUT + l];

    float acc[8];
#pragma unroll
    for (int r = 0; r < 8; ++r) acc[r] = 0.f;

#pragma unroll 1
    for (int c0 = 0; c0 < FIN; c0 += 32) {
        float wreg[32];
#pragma unroll
        for (int cc = 0; cc < 32; ++cc) wreg[cc] = W[(c0 + cc) * FOUT + l];
#pragma unroll
        for (int r = 0; r < 8; ++r) {
            const int row = w * 8 + r;
#pragma unroll
            for (int cc = 0; cc < 32; ++cc)
                acc[r] = fmaf(hT[row][c0 + cc], wreg[cc], acc[r]);  // LDS broadcast
        }
    }

#pragma unroll
    for (int r = 0; r < 8; ++r) {
        float s0 = acc[r] * a0;
        float s1 = acc[r] * a1;
#pragma unroll
        for (int off = 32; off >= 1; off >>= 1) {
            s0 += __shfl_xor(s0, off, 64);
            s1 += __shfl_xor(s1, off, 64);
        }
        if (l == 0) {
            fs[b * Nn + n0 + w * 8 + r] = s0 * LOG2E;
            fd[b * Nn + n0 + w * 8 + r] = s1 * LOG2E;
        }
    }

    u32 pk[4];
#pragma unroll
    for (int i = 0; i < 4; ++i)
        pk[i] = f2bf_bits(acc[2 * i]) | (f2bf_bits(acc[2 * i + 1]) << 16);
    const int slotg = ((b * 64 + t32) * 4 + (l >> 4)) * 64 + ((w << 4) | (l & 15));
    reinterpret_cast<uint4*>(whfrag)[slotg] = make_uint4(pk[0], pk[1], pk[2], pk[3]);
}

// Kernel 2: EXACTLY r5's structure (4 j-quarter waves, per-wave dbuf A-tile,
// lgkm fence, Z via MFMA ones), except the adj/fd prefetch is now 2-AHEAD
// through a 3-slot register ring, hand-unrolled so every index is static.
__global__ __launch_bounds__(256, 4) void gat_k2(
        const int* __restrict__ adj, const __bf16* __restrict__ whfrag,
        const float* __restrict__ fs, const float* __restrict__ fd,
        float* __restrict__ out) {
    const int blk = blockIdx.x;              // 1024 blocks
    const int b   = blk >> 7;
    const int i0  = (blk & 127) * 16;
    const int l   = threadIdx.x & 63;
    const int w   = __builtin_amdgcn_readfirstlane((int)(threadIdx.x >> 6)); // j quarter

    __shared__ __align__(16) char  aLDS[4 * 4096];  // per-wave 2x2KB double buffer
    __shared__ f32x4 comb[4][4][64];                // 16 KB combine buffer
    __shared__ float zpart[4][16];

    const int g  = l >> 4;      // row group: rows g*4 .. g*4+3
    const int jc = l & 15;      // j sub: j = jc*4 .. jc*4+3 within 64-j tile

    char* myA = aLDS + w * 4096;

    float fs_loc[4];
#pragma unroll
    for (int rr = 0; rr < 4; ++rr) fs_loc[rr] = fs[b * Nn + i0 + g * 4 + rr];

    const int    jq0  = w * 512;
    const float* fdp  = fd + b * Nn + jq0 + jc * 4;
    const int*   adj0 = adj + (size_t)(b * Nn + i0 + g * 4) * Nn + jq0 + jc * 4;

    const bf16x8* bfr = reinterpret_cast<const bf16x8*>(whfrag)
                        + (size_t)((b * 64 + w * 16) * 4) * 64 + l;

    f32x4 acc[4] = {{0,0,0,0},{0,0,0,0},{0,0,0,0},{0,0,0,0}};
    f32x4 accz   = {0.f, 0.f, 0.f, 0.f};

    bf16x8 onesv;
#pragma unroll
    for (int i = 0; i < 8; ++i) onesv[i] = (__bf16)1.0f;

    i32x4 adjR[3][4];   // 3-slot ring, 2-ahead prefetch
    f32x4 fdR[3];

    // prologue: slots 0 (tile 0) and 1 (tile 1) in flight before the loop
#pragma unroll
    for (int rr = 0; rr < 4; ++rr) {
        adjR[0][rr] = *reinterpret_cast<const i32x4*>(adj0 + (size_t)rr * Nn);
        adjR[1][rr] = *reinterpret_cast<const i32x4*>(adj0 + (size_t)rr * Nn + 64);
    }
    fdR[0] = *reinterpret_cast<const f32x4*>(fdp);
    fdR[1] = *reinterpret_cast<const f32x4*>(fdp + 64);

#define GAT_STEP(IT, CUR, PRE)                                                 \
  {                                                                            \
    if ((IT) + 2 < 8) {  /* issue tile IT+2 into ring slot PRE */              \
      _Pragma("unroll")                                                        \
      for (int rr = 0; rr < 4; ++rr)                                           \
        adjR[PRE][rr] = *reinterpret_cast<const i32x4*>(                       \
            adj0 + (size_t)rr * Nn + ((IT) + 2) * 64);                         \
      fdR[PRE] = *reinterpret_cast<const f32x4*>(fdp + ((IT) + 2) * 64);       \
    }                                                                          \
    char* buf = myA + ((IT) & 1) * 2048;                                       \
    _Pragma("unroll")                                                          \
    for (int rr = 0; rr < 4; ++rr) {                                           \
      const int row = g * 4 + rr;                                              \
      u32 wds[2];                                                              \
      _Pragma("unroll")                                                        \
      for (int hp = 0; hp < 2; ++hp) {                                         \
        float pv[2];                                                           \
        _Pragma("unroll")                                                      \
        for (int q = 0; q < 2; ++q) {                                          \
          const int jj = hp * 2 + q;                                           \
          float e  = fs_loc[rr] + fdR[CUR][jj];                                \
          float lr = fmaxf(e, 0.2f * e);       /* leaky relu (scale-safe) */   \
          float p  = exp2f(lr);                /* fs/fd pre-scaled by log2e */ \
          pv[q] = (adjR[CUR][rr][jj] > 0) ? p : 0.f;                           \
        }                                                                      \
        wds[hp] = __builtin_bit_cast(u32,                                      \
                      (bf16x2){(__bf16)pv[0], (__bf16)pv[1]});                 \
      }                                                                        \
      const int boff = (row * 128 + jc * 8) ^ ((row & 7) << 4);                \
      *reinterpret_cast<uint2*>(buf + boff) = make_uint2(wds[0], wds[1]);      \
    }                                                                          \
    asm volatile("s_waitcnt lgkmcnt(0)" ::: "memory");                         \
    __builtin_amdgcn_sched_barrier(0x20);   /* VMEM reads may hoist */         \
    {                                                                          \
      const int rb0 = (((l & 15) * 128 + g * 16) ^ ((l & 7) << 4));            \
      bf16x8 av = *reinterpret_cast<const bf16x8*>(buf + rb0);                 \
      _Pragma("unroll")                                                        \
      for (int o16 = 0; o16 < 4; ++o16)                                        \
        acc[o16] = __builtin_amdgcn_mfma_f32_16x16x32_bf16(                    \
            av, bfr[(((IT) * 2 + 0) * 4 + o16) * 64], acc[o16], 0, 0, 0);      \
      accz = __builtin_amdgcn_mfma_f32_16x16x32_bf16(av, onesv, accz, 0, 0, 0);\
    }                                                                          \
    {                                                                          \
      const int rb1 = (((l & 15) * 128 + 64 + g * 16) ^ ((l & 7) << 4));       \
      bf16x8 av = *reinterpret_cast<const bf16x8*>(buf + rb1);                 \
      _Pragma("unroll")                                                        \
      for (int o16 = 0; o16 < 4; ++o16)                                        \
        acc[o16] = __builtin_amdgcn_mfma_f32_16x16x32_bf16(                    \
            av, bfr[(((IT) * 2 + 1) * 4 + o16) * 64], acc[o16], 0, 0, 0);      \
      accz = __builtin_amdgcn_mfma_f32_16x16x32_bf16(av, onesv, accz, 0, 0, 0);\
    }                                                                          \
  }

    GAT_STEP(0, 0, 2)
    GAT_STEP(1, 1, 0)
    GAT_STEP(2, 2, 1)
    GAT_STEP(3, 0, 2)
    GAT_STEP(4, 1, 0)
    GAT_STEP(5, 2, 1)
    GAT_STEP(6, 0, 2)
    GAT_STEP(7, 1, 0)
#undef GAT_STEP

    // Z partials: accz D-frag row=(l>>4)*4+r, col=l&15 (all cols identical)
    if ((l & 15) == 0) {
#pragma unroll
        for (int r = 0; r < 4; ++r) zpart[w][(l >> 4) * 4 + r] = accz[r];
    }
#pragma unroll
    for (int o16 = 0; o16 < 4; ++o16) comb[w][o16][l] = acc[o16];
    __syncthreads();

    // wave w finalizes output column block o16 = w
    f32x4 res = comb[0][w][l];
#pragma unroll
    for (int wp = 1; wp < 4; ++wp) res += comb[wp][w][l];

#pragma unroll
    for (int r = 0; r < 4; ++r) {
        const int row = g * 4 + r;                     // C/D: row=(l>>4)*4+r, col=l&15
        float z = zpart[0][row] + zpart[1][row] + zpart[2][row] + zpart[3][row];
        float v = res[r] / z;
        v = v > 0.f ? v : expm1f(v);                   // ELU
        out[(size_t)(b * Nn + i0 + row) * FOUT + w * 16 + jc] = v;
    }
}

extern "C" void kernel_launch(void* const* d_in, const int* in_sizes, int n_in,
                              void* d_out, int out_size, void* d_ws, size_t ws_size,
                              hipStream_t stream) {
    const float* h   = (const float*)d_in[0];
    const int*   adj = (const int*)d_in[1];
    const float* W   = (const float*)d_in[2];
    const float* a   = (const float*)d_in[3];
    float* out = (float*)d_out;

    __bf16* whfrag = (__bf16*)d_ws;                                   // 2 MB
    float*  fs     = (float*)((char*)d_ws + (size_t)Bb * Nn * FOUT * 2);
    float*  fd     = fs + Bb * Nn;

    gat_k1<<<dim3(Bb * 64), dim3(256), 0, stream>>>(h, W, a, whfrag, fs, fd);
    gat_k2<<<dim3(Bb * 128), dim3(256), 0, stream>>>(adj, whfrag, fs, fd, out);
}